// Round 1
// baseline (571.911 us; speedup 1.0000x reference)
//
#include <hip/hip_runtime.h>
#include <hip/hip_bf16.h>
#include <math.h>

#define GG 2
#define NPG 332
#define NN 664
#define DEGC 32
#define EE 21248
#define KHD 6
#define KP1 166
#define KP2 83
#define DIM 332
#define DD3 128
#define MAXIN 128

// ---------------- adjacency bucket build ----------------
__global__ void k_bucket(const int* __restrict__ src, const int* __restrict__ dst,
                         const int* __restrict__ newidx, int* cnt, int* bucket, int nE) {
    int e = blockIdx.x * 256 + threadIdx.x;
    if (e >= nE) return;
    int d = dst[e];
    if (newidx) {
        int ns = newidx[src[e]];
        int nd = newidx[d];
        if (ns < 0 || nd < 0) return;
        d = nd;
    }
    int slot = atomicAdd(&cnt[d], 1);
    if (slot < MAXIN) bucket[d * MAXIN + slot] = e;
}

// ---------------- h[n][k] = relu(dot(pos_row(n), W1[:,k])) ----------------
__global__ void k_h(const float* __restrict__ pos, const float* __restrict__ W1,
                    const int* __restrict__ perm, int nn, float* __restrict__ h) {
    int t = blockIdx.x * 64 + threadIdx.x;
    if (t >= nn * KHD) return;
    int i = t / KHD, k = t % KHD;
    int row = perm ? perm[i] : i;
    const float* pr = pos + (size_t)row * DIM;
    float acc = 0.f;
    for (int j = 0; j < DIM; ++j) acc += pr[j] * W1[j * KHD + k];
    h[t] = fmaxf(acc, 0.f);
}

// ---------------- xt[n][o] = sum_k h[n][k]*(X@W2_k)[n][o] + (X@NB)[n][o] ----------------
__global__ void k_xt(const float* __restrict__ X, const float* __restrict__ W2,
                     const float* __restrict__ nb, const float* __restrict__ h,
                     float* __restrict__ xt, int nn) {
    __shared__ float Xs[16][17];
    int tx = threadIdx.x, ty = threadIdx.y;
    int o = blockIdx.x * 16 + tx;
    int n = blockIdx.y * 16 + ty;
    float acc[7] = {0.f, 0.f, 0.f, 0.f, 0.f, 0.f, 0.f};
    for (int i0 = 0; i0 < DIM; i0 += 16) {
        int ii = i0 + tx;
        Xs[ty][tx] = (n < nn && ii < DIM) ? X[n * DIM + ii] : 0.f;
        __syncthreads();
        int lim = (DIM - i0) < 16 ? (DIM - i0) : 16;
        if (o < DIM) {
            for (int t = 0; t < lim; ++t) {
                float xv = Xs[ty][t];
                int i = i0 + t;
#pragma unroll
                for (int k = 0; k < 6; ++k)
                    acc[k] += xv * W2[k * (DIM * DIM) + i * DIM + o];
                acc[6] += xv * nb[i * DIM + o];
            }
        }
        __syncthreads();
    }
    if (n < nn && o < DIM) {
        float r = acc[6];
#pragma unroll
        for (int k = 0; k < 6; ++k) r += h[n * KHD + k] * acc[k];
        xt[n * DIM + o] = r;
    }
}

// ---------------- softmax-weighted aggregation + bias ----------------
__global__ void k_agg(const float* __restrict__ xt, const int* __restrict__ cnt,
                      const int* __restrict__ bucket, const int* __restrict__ srcArr,
                      const float* __restrict__ eattr, const int* __restrict__ newidx,
                      const float* __restrict__ bias, float* __restrict__ out, int nn) {
    __shared__ float alpha[MAXIN];
    __shared__ int sidx[MAXIN];
    __shared__ float red[128];
    int n = blockIdx.x;
    int t = threadIdx.x;
    int c = cnt[n];
    if (c > MAXIN) c = MAXIN;
    float mysum = 0.f;
    for (int j = t; j < c; j += 128) {
        int e = bucket[n * MAXIN + j];
        int s = srcArr[e];
        if (newidx) s = newidx[s];
        float ex = expf(eattr[e]);
        alpha[j] = ex;
        sidx[j] = s;
        mysum += ex;
    }
    red[t] = mysum;
    __syncthreads();
    for (int off = 64; off > 0; off >>= 1) {
        if (t < off) red[t] += red[t + off];
        __syncthreads();
    }
    const float eself = 2.718281828459045f; // expf(1)
    float inv = 1.f / (red[0] + eself);
    __syncthreads();
    for (int j = t; j < c; j += 128) alpha[j] *= inv;
    __syncthreads();
    float aself = eself * inv;
    for (int o = t; o < DIM; o += 128) {
        float acc = bias[o] + aself * xt[n * DIM + o];
        for (int j = 0; j < c; ++j) acc += alpha[j] * xt[sidx[j] * DIM + o];
        out[n * DIM + o] = acc;
    }
}

// ---------------- score[n] = sigmoid(dot(xv[n],w)/||w||) ----------------
__global__ void k_score(const float* __restrict__ xv, const float* __restrict__ w,
                        float* __restrict__ score, int nn) {
    int n = blockIdx.x, t = threadIdx.x;
    float a = 0.f, b = 0.f;
    for (int j = t; j < DIM; j += 64) {
        float wv = w[j];
        a += xv[n * DIM + j] * wv;
        b += wv * wv;
    }
    for (int off = 32; off > 0; off >>= 1) {
        a += __shfl_down(a, off);
        b += __shfl_down(b, off);
    }
    if (t == 0) score[n] = 1.f / (1.f + expf(-a / sqrtf(b)));
}

// ---------------- per-graph stable top-k via O(n^2) rank ----------------
__global__ void k_topk(const float* __restrict__ score, int n_per, int k,
                       int* __restrict__ perm, int* __restrict__ newidx) {
    __shared__ float s[NPG];
    int g = blockIdx.x, t = threadIdx.x;
    for (int i = t; i < n_per; i += blockDim.x) s[i] = score[g * n_per + i];
    __syncthreads();
    for (int i = t; i < n_per; i += blockDim.x) {
        float si = s[i];
        int r = 0;
        for (int j = 0; j < n_per; ++j) {
            float sj = s[j];
            r += (sj > si) || (sj == si && j < i);
        }
        int node = g * n_per + i;
        if (r < k) {
            perm[g * k + r] = node;
            newidx[node] = g * k + r;
        } else {
            newidx[node] = -1;
        }
    }
}

// ---------------- x_new = xv[perm]*score[perm] ----------------
__global__ void k_xnew(const float* __restrict__ xv, const float* __restrict__ score,
                       const int* __restrict__ perm, float* __restrict__ xnew, int nk) {
    int idx = blockIdx.x * 256 + threadIdx.x;
    if (idx >= nk * DIM) return;
    int r = idx / DIM, o = idx % DIM;
    int p = perm[r];
    xnew[idx] = xv[p * DIM + o] * score[p];
}

// ---------------- readout: [max ; mean] per graph into z ----------------
__global__ void k_readout(const float* __restrict__ xnew, int k, float kf,
                          float* __restrict__ z, int base) {
    int idx = blockIdx.x * 64 + threadIdx.x;
    if (idx >= GG * DIM) return;
    int g = idx / DIM, o = idx % DIM;
    float mx = -3.4e38f, sm = 0.f;
    for (int i = 0; i < k; ++i) {
        float v = xnew[(g * k + i) * DIM + o];
        mx = fmaxf(mx, v);
        sm += v;
    }
    z[g * 1328 + base + o] = mx;
    z[g * 1328 + base + DIM + o] = sm / kf;
}

// ---------------- head: fc + bn(G=2) + relu ----------------
__global__ void k_fc1(const float* __restrict__ z, const float* __restrict__ W,
                      const float* __restrict__ b, const float* __restrict__ gm,
                      const float* __restrict__ bt, float* __restrict__ z1) {
    int j = blockIdx.x * 128 + threadIdx.x;
    if (j >= DIM) return;
    float a0 = 0.f, a1 = 0.f;
    for (int i = 0; i < 1328; ++i) {
        float wv = W[i * DIM + j];
        a0 += z[i] * wv;
        a1 += z[1328 + i] * wv;
    }
    a0 += b[j]; a1 += b[j];
    float m = 0.5f * (a0 + a1);
    float v = 0.5f * ((a0 - m) * (a0 - m) + (a1 - m) * (a1 - m));
    float is = 1.f / sqrtf(v + 1e-5f);
    float g_ = gm[j], bb = bt[j];
    z1[j]       = fmaxf((a0 - m) * is * g_ + bb, 0.f);
    z1[DIM + j] = fmaxf((a1 - m) * is * g_ + bb, 0.f);
}

__global__ void k_fc2(const float* __restrict__ z1, const float* __restrict__ W,
                      const float* __restrict__ b, const float* __restrict__ gm,
                      const float* __restrict__ bt, float* __restrict__ z2) {
    int j = threadIdx.x;
    if (j >= DD3) return;
    float a0 = 0.f, a1 = 0.f;
    for (int i = 0; i < DIM; ++i) {
        float wv = W[i * DD3 + j];
        a0 += z1[i] * wv;
        a1 += z1[DIM + i] * wv;
    }
    a0 += b[j]; a1 += b[j];
    float m = 0.5f * (a0 + a1);
    float v = 0.5f * ((a0 - m) * (a0 - m) + (a1 - m) * (a1 - m));
    float is = 1.f / sqrtf(v + 1e-5f);
    float g_ = gm[j], bb = bt[j];
    z2[j]       = fmaxf((a0 - m) * is * g_ + bb, 0.f);
    z2[DD3 + j] = fmaxf((a1 - m) * is * g_ + bb, 0.f);
}

__global__ void k_fc3(const float* __restrict__ z2, const float* __restrict__ W,
                      const float* __restrict__ b, float* __restrict__ out) {
    int t = threadIdx.x;
    if (t >= GG * 2) return;
    int g = t / 2, c = t % 2;
    float acc = b[c];
    for (int i = 0; i < DD3; ++i) acc += z2[g * DD3 + i] * W[i * 2 + c];
    out[g * 2 + c] = acc;
}

extern "C" void kernel_launch(void* const* d_in, const int* in_sizes, int n_in,
                              void* d_out, int out_size, void* d_ws, size_t ws_size,
                              hipStream_t stream) {
    (void)in_sizes; (void)n_in; (void)out_size; (void)ws_size;
    const float* x     = (const float*)d_in[0];
    const int*   eidx  = (const int*)d_in[1];
    const float* eattr = (const float*)d_in[3];
    const float* pos   = (const float*)d_in[4];
    const float* c1W1  = (const float*)d_in[6];
    const float* c1W2  = (const float*)d_in[7];
    const float* c1nb  = (const float*)d_in[8];
    const float* c1b   = (const float*)d_in[9];
    const float* p1w   = (const float*)d_in[10];
    const float* c2W1  = (const float*)d_in[11];
    const float* c2W2  = (const float*)d_in[12];
    const float* c2nb  = (const float*)d_in[13];
    const float* c2b   = (const float*)d_in[14];
    const float* p2w   = (const float*)d_in[15];
    const float* fc1W  = (const float*)d_in[16];
    const float* fc1b  = (const float*)d_in[17];
    const float* bn1g  = (const float*)d_in[18];
    const float* bn1b  = (const float*)d_in[19];
    const float* fc2W  = (const float*)d_in[20];
    const float* fc2b  = (const float*)d_in[21];
    const float* bn2g  = (const float*)d_in[22];
    const float* bn2b  = (const float*)d_in[23];
    const float* fc3W  = (const float*)d_in[24];
    const float* fc3b  = (const float*)d_in[25];

    const int* src = eidx;
    const int* dst = eidx + EE;

    // workspace carve (256B aligned)
    char* w = (char*)d_ws;
    auto alloc = [&](size_t bytes) { void* p = (void*)w; w += ((bytes + 255) / 256) * 256; return p; };
    int*   cnt1    = (int*)alloc(NN * 4);
    int*   bucket1 = (int*)alloc((size_t)NN * MAXIN * 4);
    float* h1      = (float*)alloc(NN * KHD * 4);
    float* xt1     = (float*)alloc((size_t)NN * DIM * 4);
    float* out1    = (float*)alloc((size_t)NN * DIM * 4);
    float* score1  = (float*)alloc(NN * 4);
    int*   perm1   = (int*)alloc(GG * KP1 * 4);
    int*   newidx1 = (int*)alloc(NN * 4);
    float* x1p     = (float*)alloc((size_t)GG * KP1 * DIM * 4);
    float* zbuf    = (float*)alloc(GG * 1328 * 4);
    int*   cnt2    = (int*)alloc(GG * KP1 * 4);
    int*   bucket2 = (int*)alloc((size_t)GG * KP1 * MAXIN * 4);
    float* h2      = (float*)alloc(GG * KP1 * KHD * 4);
    float* xt2     = (float*)alloc((size_t)GG * KP1 * DIM * 4);
    float* out2    = (float*)alloc((size_t)GG * KP1 * DIM * 4);
    float* score2  = (float*)alloc(GG * KP1 * 4);
    int*   perm2   = (int*)alloc(GG * KP2 * 4);
    int*   newidx2 = (int*)alloc(GG * KP1 * 4);
    float* x2p     = (float*)alloc((size_t)GG * KP2 * DIM * 4);
    float* z1      = (float*)alloc(GG * DIM * 4);
    float* z2      = (float*)alloc(GG * DD3 * 4);

    // ---- conv1 ----
    hipMemsetAsync(cnt1, 0, NN * 4, stream);
    k_bucket<<<(EE + 255) / 256, 256, 0, stream>>>(src, dst, nullptr, cnt1, bucket1, EE);
    k_h<<<(NN * KHD + 63) / 64, 64, 0, stream>>>(pos, c1W1, nullptr, NN, h1);
    k_xt<<<dim3(21, (NN + 15) / 16), dim3(16, 16), 0, stream>>>(x, c1W2, c1nb, h1, xt1, NN);
    k_agg<<<NN, 128, 0, stream>>>(xt1, cnt1, bucket1, src, eattr, nullptr, c1b, out1, NN);

    // ---- pool1 + readout1 ----
    k_score<<<NN, 64, 0, stream>>>(out1, p1w, score1, NN);
    k_topk<<<GG, 384, 0, stream>>>(score1, NPG, KP1, perm1, newidx1);
    k_xnew<<<(GG * KP1 * DIM + 255) / 256, 256, 0, stream>>>(out1, score1, perm1, x1p, GG * KP1);
    k_readout<<<(GG * DIM + 63) / 64, 64, 0, stream>>>(x1p, KP1, (float)KP1, zbuf, 0);

    // ---- conv2 ----
    hipMemsetAsync(cnt2, 0, GG * KP1 * 4, stream);
    k_bucket<<<(EE + 255) / 256, 256, 0, stream>>>(src, dst, newidx1, cnt2, bucket2, EE);
    k_h<<<(GG * KP1 * KHD + 63) / 64, 64, 0, stream>>>(pos, c2W1, perm1, GG * KP1, h2);
    k_xt<<<dim3(21, (GG * KP1 + 15) / 16), dim3(16, 16), 0, stream>>>(x1p, c2W2, c2nb, h2, xt2, GG * KP1);
    k_agg<<<GG * KP1, 128, 0, stream>>>(xt2, cnt2, bucket2, src, eattr, newidx1, c2b, out2, GG * KP1);

    // ---- pool2 + readout2 ----
    k_score<<<GG * KP1, 64, 0, stream>>>(out2, p2w, score2, GG * KP1);
    k_topk<<<GG, 384, 0, stream>>>(score2, KP1, KP2, perm2, newidx2);
    k_xnew<<<(GG * KP2 * DIM + 255) / 256, 256, 0, stream>>>(out2, score2, perm2, x2p, GG * KP2);
    k_readout<<<(GG * DIM + 63) / 64, 64, 0, stream>>>(x2p, KP2, (float)KP2, zbuf, 664);

    // ---- head ----
    k_fc1<<<3, 128, 0, stream>>>(zbuf, fc1W, fc1b, bn1g, bn1b, z1);
    k_fc2<<<1, 128, 0, stream>>>(z1, fc2W, fc2b, bn2g, bn2b, z2);
    k_fc3<<<1, 64, 0, stream>>>(z2, fc3W, fc3b, (float*)d_out);
}